// Round 3
// baseline (1198.055 us; speedup 1.0000x reference)
//
#include <hip/hip_runtime.h>
#include <hip/hip_bf16.h>

typedef unsigned int uint;
typedef _Float16 f16;
typedef _Float16 f16x8 __attribute__((ext_vector_type(8)));
typedef float f32x4 __attribute__((ext_vector_type(4)));

#define T_STEPS 100

// ---------------- ws layout (bytes), with overlays ----------------
// Region A: h1 [16][64][28][28] f32 = 3,211,264   (dead after k_lif1pool)
//   overlay: whi packed 73,728 @0 ; wlo packed 73,728 @73,728
#define OFF_H1   (size_t)0
#define OFF_WHI  (size_t)0
#define OFF_WLO  (size_t)73728
// p1: [100*16 imgs][256 pix][64 ci] u8 = 26,214,400
#define OFF_P1   (size_t)3211264
// h2: [1600][64][196] f32 = 80,281,600            (dead after k_lif2pool)
//   overlay: h3 [100][16][1024] f32 = 6,553,600 ; s3 u8 1,638,400 ; h4 f32 64,000
#define OFF_H2   (size_t)29425664
#define OFF_H3   (size_t)29425664
#define OFF_S3   (size_t)35979264
#define OFF_H4   (size_t)37617664
// p2: [100][16][3136] u8 = 5,017,600  (ends 114,724,864 <= proven ws usage)
#define OFF_P2   (size_t)109707264

__device__ __forceinline__ int lif_step_i(float& v, float x) {
  // v = v + (x - v)/2  (multiply by 0.5 is exact, identical rounding to reference)
  v = __fadd_rn(v, __fmul_rn(__fsub_rn(x, v), 0.5f));
  if (v >= 1.0f) { v = 0.0f; return 1; }
  return 0;
}

// ---------------- weight prep: fragment-major fp16 hi/lo split ----------------
// K order: k = (dy*3+dx)*64 + ci, K=576 -> 18 k-blocks of 32.
// packed index i = ((kb*4 + cb)*64 + lane)*8 + j
//   -> k = kb*32 + (lane>>4)*8 + j ; co = cb*16 + (lane&15)
__global__ __launch_bounds__(256) void k_prep_w2(const float* __restrict__ w2,
                                                 f16* __restrict__ whi, f16* __restrict__ wlo) {
  int i = blockIdx.x * 256 + threadIdx.x;       // < 36864
  int j = i & 7, l = (i >> 3) & 63, cb = (i >> 9) & 3, kb = i >> 11;
  int k = kb * 32 + (l >> 4) * 8 + j;
  int co = cb * 16 + (l & 15);
  int ci = k & 63, tap = k >> 6;
  int dy = tap / 3, dx = tap - 3 * dy;
  float w = w2[((co * 64 + ci) * 3 + dy) * 3 + dx];
  // avoid fp16-denormal hi: push tiny weights entirely into lo (lo scaled by 2^12)
  float hif = (fabsf(w) < 6.104e-5f) ? 0.0f : (float)(f16)w;
  whi[i] = (f16)hif;
  wlo[i] = (f16)((w - hif) * 4096.0f);
}

__global__ __launch_bounds__(256) void k_zero_h3(float4* __restrict__ p) {
  p[blockIdx.x * 256 + threadIdx.x] = make_float4(0.f, 0.f, 0.f, 0.f);
}

// ---------------- conv1 + BN1 ----------------
__global__ __launch_bounds__(256) void k_conv1(const float* __restrict__ x, const float* __restrict__ w1,
                                               const float* __restrict__ g1, const float* __restrict__ b1,
                                               const float* __restrict__ m1, const float* __restrict__ v1,
                                               float* __restrict__ h1) {
  int i = blockIdx.x * 256 + threadIdx.x;      // < 802816
  int pos = i % 784;
  int bc  = i / 784;
  int c = bc & 63, b = bc >> 6;
  int y = pos / 28, xx = pos % 28;
  float a = 0.f;
#pragma unroll
  for (int dy = 0; dy < 3; ++dy) {
    int iy = y + dy - 1;
#pragma unroll
    for (int dx = 0; dx < 3; ++dx) {
      int ix = xx + dx - 1;
      if (iy >= 0 && iy < 28 && ix >= 0 && ix < 28)
        a = fmaf(w1[c * 9 + dy * 3 + dx], x[b * 784 + iy * 28 + ix], a);
    }
  }
  float inv  = g1[c] / sqrtf(v1[c] + 1e-5f);
  float bias = __fsub_rn(b1[c], __fmul_rn(m1[c], inv));
  h1[i] = __fadd_rn(__fmul_rn(a, inv), bias);
}

// ---------------- LIF1 + maxpool -> p1 (u8, channels-last halo [pix=y*16+x][ci]) ----------------
__global__ __launch_bounds__(256) void k_lif1pool(const float* __restrict__ h1,
                                                  unsigned char* __restrict__ p1) {
  int t = blockIdx.x * 256 + threadIdx.x;      // < 262144 = 16b*16y*16x*64ci
  int ci = t & 63, xx = (t >> 6) & 15, y = (t >> 10) & 15, b = t >> 14;
  int pix = y * 16 + xx;
  size_t outbase = (size_t)b * 16384 + pix * 64 + ci;
  const size_t tstride = (size_t)16 * 16384;
  if (y == 0 || y == 15 || xx == 0 || xx == 15) {
    for (int tt = 0; tt < T_STEPS; ++tt) p1[outbase + (size_t)tt * tstride] = 0;
    return;
  }
  int py = y - 1, px = xx - 1;
  const float* hp = h1 + ((size_t)(b * 64 + ci) * 28 + 2 * py) * 28 + 2 * px;
  float h00 = hp[0], h01 = hp[1], h10 = hp[28], h11 = hp[29];
  float v00 = 0.f, v01 = 0.f, v10 = 0.f, v11 = 0.f;
  for (int tt = 0; tt < T_STEPS; ++tt) {
    int s = 0;
    s |= lif_step_i(v00, h00);
    s |= lif_step_i(v01, h01);
    s |= lif_step_i(v10, h10);
    s |= lif_step_i(v11, h11);
    p1[outbase + (size_t)tt * tstride] = (unsigned char)s;
  }
}

// ---------------- conv2 + BN2 via MFMA (fp16 hi/lo exact split) ----------------
// block = 1 image, 256 thr (4 waves). LDS: f16 image [258 pix][64 ci], XOR-swizzled rows.
// wave w: cohalf = w&1 (co 32*cohalf..+32, two 16x16 MFMA row-blocks), oy rows (w>>1)*7..+7.
// MFMA 16x16x32_f16: A=weights (row=co=lane&15, k=(lane>>4)*8+j), B=spikes (col=ox=lane&15).
// N-tile = one oy row x 16 ox lanes (ox 14,15 computed, discarded).
__global__ __launch_bounds__(256, 4) void k_conv2(const unsigned char* __restrict__ p1,
                                                  const f16* __restrict__ whi, const f16* __restrict__ wlo,
                                                  const float* __restrict__ g2, const float* __restrict__ b2,
                                                  const float* __restrict__ m2, const float* __restrict__ v2,
                                                  float* __restrict__ h2) {
  __shared__ unsigned char smem[33024];        // 258 rows * 128B
  const int tid = threadIdx.x;
  const int tb = blockIdx.x;
  const unsigned char* img = p1 + (size_t)tb * 16384;
  // stage: u8 [256 pix][64 ci] -> f16 LDS, swizzled: byte = pix*128 + ((ci*2) ^ ((pix&7)<<4))
#pragma unroll
  for (int it = 0; it < 4; ++it) {
    int s = it * 256 + tid;                    // 16B slot: pix = s>>2, c4 = s&3
    uint4 d = *(const uint4*)(img + (size_t)s * 16);
    int pix = s >> 2, c4 = s & 3;
    uint dw[4] = {d.x, d.y, d.z, d.w};
    f16x8 va, vb;
#pragma unroll
    for (int e = 0; e < 8; ++e) {
      va[e] = (f16)(float)((dw[e >> 2] >> ((e & 3) * 8)) & 255u);
      vb[e] = (f16)(float)((dw[2 + (e >> 2)] >> ((e & 3) * 8)) & 255u);
    }
    int rowbase = pix * 128;
    int sw = (pix & 7) << 4;
    *(f16x8*)(smem + rowbase + ((c4 * 32) ^ sw)) = va;
    *(f16x8*)(smem + rowbase + ((c4 * 32 + 16) ^ sw)) = vb;
  }
  if (tid < 16) *(uint4*)(smem + 32768 + tid * 16) = make_uint4(0u, 0u, 0u, 0u);
  __syncthreads();

  const int lane = tid & 63;
  const int wave = tid >> 6;
  const int ox = lane & 15;
  const int g = lane >> 4;
  const int cohalf = wave & 1;
  const int pb0 = (wave >> 1) * 7;
  // hoist BN constants for this lane's 8 co values
  float binv[2][4], bofs[2][4];
#pragma unroll
  for (int cb = 0; cb < 2; ++cb)
#pragma unroll
    for (int r = 0; r < 4; ++r) {
      int co = (cohalf * 2 + cb) * 16 + g * 4 + r;
      float iv = g2[co] / sqrtf(v2[co] + 1e-5f);
      binv[cb][r] = iv;
      bofs[cb][r] = __fsub_rn(b2[co], __fmul_rn(m2[co], iv));
    }

  for (int oy = pb0; oy < pb0 + 7; ++oy) {
    f32x4 aH0 = {0.f, 0.f, 0.f, 0.f}, aL0 = {0.f, 0.f, 0.f, 0.f};
    f32x4 aH1 = {0.f, 0.f, 0.f, 0.f}, aL1 = {0.f, 0.f, 0.f, 0.f};
#pragma unroll
    for (int kb = 0; kb < 18; ++kb) {
      const int tap = kb >> 1;
      const int dy = tap / 3, dx = tap - 3 * dy;
      const int cilo2 = (kb & 1) * 64;         // byte offset of ci-block within row
      int pix = (oy + dy) * 16 + ox + dx;
      int boff = pix * 128 + ((cilo2 + g * 16) ^ ((pix & 7) << 4));
      f16x8 bf = *(const f16x8*)(smem + boff);
      size_t abase = ((size_t)(kb * 4 + cohalf * 2) * 64 + lane) * 8;
      f16x8 ah0 = *(const f16x8*)(whi + abase);
      f16x8 al0 = *(const f16x8*)(wlo + abase);
      f16x8 ah1 = *(const f16x8*)(whi + abase + 512);
      f16x8 al1 = *(const f16x8*)(wlo + abase + 512);
      aH0 = __builtin_amdgcn_mfma_f32_16x16x32_f16(ah0, bf, aH0, 0, 0, 0);
      aL0 = __builtin_amdgcn_mfma_f32_16x16x32_f16(al0, bf, aL0, 0, 0, 0);
      aH1 = __builtin_amdgcn_mfma_f32_16x16x32_f16(ah1, bf, aH1, 0, 0, 0);
      aL1 = __builtin_amdgcn_mfma_f32_16x16x32_f16(al1, bf, aL1, 0, 0, 0);
    }
    if (ox < 14) {
#pragma unroll
      for (int r = 0; r < 4; ++r) {
        int co0 = cohalf * 32 + g * 4 + r;
        float s0 = __fadd_rn(aH0[r], __fmul_rn(aL0[r], 1.0f / 4096.0f));
        h2[((size_t)tb * 64 + co0) * 196 + oy * 14 + ox] =
            __fadd_rn(__fmul_rn(s0, binv[0][r]), bofs[0][r]);
        int co1 = co0 + 16;
        float s1 = __fadd_rn(aH1[r], __fmul_rn(aL1[r], 1.0f / 4096.0f));
        h2[((size_t)tb * 64 + co1) * 196 + oy * 14 + ox] =
            __fadd_rn(__fmul_rn(s1, binv[1][r]), bofs[1][r]);
      }
    }
  }
}

// ---------------- LIF2 + maxpool -> p2 (u8) ----------------
__global__ __launch_bounds__(256) void k_lif2pool(const float* __restrict__ h2,
                                                  unsigned char* __restrict__ p2) {
  int t = blockIdx.x * 256 + threadIdx.x;      // < 50176 = 16*64*49
  int px = t % 7;
  int r1 = t / 7;
  int py = r1 % 7;
  int r2 = r1 / 7;
  int c = r2 & 63, b = r2 >> 6;
  const float* base = h2 + ((size_t)b * 64 + c) * 196 + (2 * py) * 14 + 2 * px;
  const size_t tstride = (size_t)16 * 64 * 196;
  unsigned char* op = p2 + (size_t)b * 3136 + c * 49 + py * 7 + px;
  const size_t otstride = (size_t)16 * 3136;
  float v00 = 0.f, v01 = 0.f, v10 = 0.f, v11 = 0.f;
#pragma unroll 4
  for (int tt = 0; tt < T_STEPS; ++tt) {
    const float* hp = base + (size_t)tt * tstride;
    float2 r0 = *(const float2*)(hp);
    float2 r1v = *(const float2*)(hp + 14);
    int s = 0;
    s |= lif_step_i(v00, r0.x);
    s |= lif_step_i(v01, r0.y);
    s |= lif_step_i(v10, r1v.x);
    s |= lif_step_i(v11, r1v.y);
    op[(size_t)tt * otstride] = (unsigned char)s;
  }
}

// ---------------- FC1: h3[tb][o] += p2[tb][:] . Wfc1[o][:] ----------------
// grid (13, 8, 2): 128tb x 128o tiles, split-K=2, atomicAdd into zeroed h3
// (exactly 2 atomic adds per cell onto 0.0 => deterministic by fp-add commutativity)
__global__ __launch_bounds__(256) void k_fc1(const unsigned char* __restrict__ p2,
                                             const float* __restrict__ wfc1,
                                             float* __restrict__ h3) {
  __shared__ float As[32][128];
  __shared__ float Bs[32][128];
  const int t = threadIdx.x;
  const int r = t & 127, half = t >> 7;
  const int tb0 = blockIdx.x * 128;
  const int o0  = blockIdx.y * 128;
  const int k0  = blockIdx.z * 1568;
  const int ig = t >> 4, jg = t & 15;
  float acc[8][8];
#pragma unroll
  for (int a = 0; a < 8; ++a)
#pragma unroll
    for (int bb = 0; bb < 8; ++bb) acc[a][bb] = 0.f;

  for (int ch = 0; ch < 49; ++ch) {
    int kb = k0 + ch * 32;
    __syncthreads();
    {
      int tb = tb0 + r;
      uint4 bytes = make_uint4(0u, 0u, 0u, 0u);
      if (tb < 1600) bytes = *(const uint4*)(p2 + (size_t)tb * 3136 + kb + half * 16);
      uint w4[4] = {bytes.x, bytes.y, bytes.z, bytes.w};
#pragma unroll
      for (int j = 0; j < 16; ++j)
        As[half * 16 + j][r] = (float)((w4[j >> 2] >> ((j & 3) * 8)) & 255u);
    }
    {
      const float* wrow = wfc1 + (size_t)(o0 + r) * 3136 + kb + half * 16;
#pragma unroll
      for (int j = 0; j < 4; ++j) {
        float4 d = *(const float4*)(wrow + j * 4);
        int kk = half * 16 + j * 4;
        Bs[kk + 0][r] = d.x; Bs[kk + 1][r] = d.y; Bs[kk + 2][r] = d.z; Bs[kk + 3][r] = d.w;
      }
    }
    __syncthreads();
#pragma unroll 8
    for (int kk = 0; kk < 32; ++kk) {
      float4 a0 = *(const float4*)&As[kk][ig * 8];
      float4 a1 = *(const float4*)&As[kk][ig * 8 + 4];
      float4 b0 = *(const float4*)&Bs[kk][jg * 8];
      float4 b1 = *(const float4*)&Bs[kk][jg * 8 + 4];
      float av[8] = {a0.x, a0.y, a0.z, a0.w, a1.x, a1.y, a1.z, a1.w};
      float bv[8] = {b0.x, b0.y, b0.z, b0.w, b1.x, b1.y, b1.z, b1.w};
#pragma unroll
      for (int a = 0; a < 8; ++a)
#pragma unroll
        for (int bb = 0; bb < 8; ++bb)
          acc[a][bb] = fmaf(av[a], bv[bb], acc[a][bb]);
    }
  }
#pragma unroll
  for (int a = 0; a < 8; ++a) {
    int tb = tb0 + ig * 8 + a;
    if (tb < 1600) {
#pragma unroll
      for (int bb = 0; bb < 8; ++bb)
        atomicAdd(&h3[(size_t)tb * 1024 + o0 + jg * 8 + bb], acc[a][bb]);
    }
  }
}

// ---------------- LIF3 -> s3 (u8) ----------------
__global__ __launch_bounds__(256) void k_lif3(const float* __restrict__ h3,
                                              unsigned char* __restrict__ s3) {
  int t = blockIdx.x * 256 + threadIdx.x;      // < 16384
  int o = t & 1023, b = t >> 10;
  size_t base = (size_t)b * 1024 + o;
  float v = 0.f;
#pragma unroll 5
  for (int tt = 0; tt < T_STEPS; ++tt) {
    float xv = h3[base + (size_t)tt * 16384];
    s3[base + (size_t)tt * 16384] = (unsigned char)lif_step_i(v, xv);
  }
}

// ---------------- FC2 ----------------
__global__ __launch_bounds__(64) void k_fc2(const unsigned char* __restrict__ s3,
                                            const float* __restrict__ wfc2,
                                            float* __restrict__ h4) {
  int tb = blockIdx.x;                          // < 1600
  int l = threadIdx.x;
  const unsigned char* srow = s3 + (size_t)tb * 1024;
  float p[10];
#pragma unroll
  for (int o = 0; o < 10; ++o) p[o] = 0.f;
  for (int j = 0; j < 16; ++j) {
    int k = l + j * 64;
    float s = (float)srow[k];
#pragma unroll
    for (int o = 0; o < 10; ++o)
      p[o] = fmaf(s, wfc2[o * 1024 + k], p[o]);
  }
#pragma unroll
  for (int o = 0; o < 10; ++o) {
    float v = p[o];
    for (int off = 32; off > 0; off >>= 1) v += __shfl_down(v, off, 64);
    if (l == 0) h4[(size_t)tb * 10 + o] = v;
  }
}

// ---------------- LIF4 + mean ----------------
__global__ __launch_bounds__(256) void k_lif4mean(const float* __restrict__ h4,
                                                  float* __restrict__ out) {
  int t = threadIdx.x;
  if (t >= 160) return;
  int o = t % 10, b = t / 10;
  float v = 0.f;
  int cnt = 0;
#pragma unroll 10
  for (int tt = 0; tt < T_STEPS; ++tt) {
    float xv = h4[(size_t)tt * 160 + b * 10 + o];
    cnt += lif_step_i(v, xv);
  }
  out[b * 10 + o] = (float)cnt / 100.0f;
}

extern "C" void kernel_launch(void* const* d_in, const int* in_sizes, int n_in,
                              void* d_out, int out_size, void* d_ws, size_t ws_size,
                              hipStream_t stream) {
  const float* x    = (const float*)d_in[0];
  const float* W1   = (const float*)d_in[1];
  const float* g1   = (const float*)d_in[2];
  const float* b1   = (const float*)d_in[3];
  const float* m1   = (const float*)d_in[4];
  const float* v1   = (const float*)d_in[5];
  const float* W2   = (const float*)d_in[6];
  const float* g2   = (const float*)d_in[7];
  const float* b2   = (const float*)d_in[8];
  const float* m2   = (const float*)d_in[9];
  const float* v2   = (const float*)d_in[10];
  const float* Wfc1 = (const float*)d_in[11];
  const float* Wfc2 = (const float*)d_in[12];
  float* out = (float*)d_out;
  char* ws = (char*)d_ws;

  float*         h1  = (float*)(ws + OFF_H1);
  f16*           whi = (f16*)(ws + OFF_WHI);
  f16*           wlo = (f16*)(ws + OFF_WLO);
  unsigned char* p1  = (unsigned char*)(ws + OFF_P1);
  float*         h2  = (float*)(ws + OFF_H2);
  unsigned char* p2  = (unsigned char*)(ws + OFF_P2);
  float*         h3  = (float*)(ws + OFF_H3);
  unsigned char* s3  = (unsigned char*)(ws + OFF_S3);
  float*         h4  = (float*)(ws + OFF_H4);

  k_conv1<<<3136, 256, 0, stream>>>(x, W1, g1, b1, m1, v1, h1);
  k_lif1pool<<<1024, 256, 0, stream>>>(h1, p1);
  k_prep_w2<<<144, 256, 0, stream>>>(W2, whi, wlo);   // overlays dead h1
  k_conv2<<<1600, 256, 0, stream>>>(p1, whi, wlo, g2, b2, m2, v2, h2);
  k_lif2pool<<<196, 256, 0, stream>>>(h2, p2);
  k_zero_h3<<<1600, 256, 0, stream>>>((float4*)h3);   // overlays dead h2
  dim3 gfc1(13, 8, 2);
  k_fc1<<<gfc1, 256, 0, stream>>>(p2, Wfc1, h3);
  k_lif3<<<64, 256, 0, stream>>>(h3, s3);
  k_fc2<<<1600, 64, 0, stream>>>(s3, Wfc2, h4);
  k_lif4mean<<<1, 256, 0, stream>>>(h4, out);
}

// Round 4
// 523.011 us; speedup vs baseline: 2.2907x; 2.2907x over previous
//
#include <hip/hip_runtime.h>
#include <hip/hip_bf16.h>

typedef unsigned int uint;
typedef _Float16 f16;
typedef _Float16 f16x8 __attribute__((ext_vector_type(8)));
typedef float f32x4 __attribute__((ext_vector_type(4)));

#define T_STEPS 100

// ---------------- ws layout (bytes), with overlays ----------------
#define OFF_H1   (size_t)0
#define OFF_WHI  (size_t)0
#define OFF_WLO  (size_t)73728
#define OFF_P1   (size_t)3211264
#define OFF_H2   (size_t)29425664
#define OFF_H3   (size_t)29425664
#define OFF_S3   (size_t)35979264
#define OFF_H4   (size_t)37617664
#define OFF_P2   (size_t)109707264

__device__ __forceinline__ int lif_step_i(float& v, float x) {
  v = __fadd_rn(v, __fmul_rn(__fsub_rn(x, v), 0.5f));
  if (v >= 1.0f) { v = 0.0f; return 1; }
  return 0;
}

// ---------------- weight prep: fragment-major fp16 hi/lo split ----------------
__global__ __launch_bounds__(256) void k_prep_w2(const float* __restrict__ w2,
                                                 f16* __restrict__ whi, f16* __restrict__ wlo) {
  int i = blockIdx.x * 256 + threadIdx.x;       // < 36864
  int j = i & 7, l = (i >> 3) & 63, cb = (i >> 9) & 3, kb = i >> 11;
  int k = kb * 32 + (l >> 4) * 8 + j;
  int co = cb * 16 + (l & 15);
  int ci = k & 63, tap = k >> 6;
  int dy = tap / 3, dx = tap - 3 * dy;
  float w = w2[((co * 64 + ci) * 3 + dy) * 3 + dx];
  float hif = (fabsf(w) < 6.104e-5f) ? 0.0f : (float)(f16)w;
  whi[i] = (f16)hif;
  wlo[i] = (f16)((w - hif) * 4096.0f);
}

__global__ __launch_bounds__(256) void k_zero_h3(float4* __restrict__ p) {
  p[blockIdx.x * 256 + threadIdx.x] = make_float4(0.f, 0.f, 0.f, 0.f);
}

// ---------------- conv1 + BN1 ----------------
__global__ __launch_bounds__(256) void k_conv1(const float* __restrict__ x, const float* __restrict__ w1,
                                               const float* __restrict__ g1, const float* __restrict__ b1,
                                               const float* __restrict__ m1, const float* __restrict__ v1,
                                               float* __restrict__ h1) {
  int i = blockIdx.x * 256 + threadIdx.x;      // < 802816
  int pos = i % 784;
  int bc  = i / 784;
  int c = bc & 63, b = bc >> 6;
  int y = pos / 28, xx = pos % 28;
  float a = 0.f;
#pragma unroll
  for (int dy = 0; dy < 3; ++dy) {
    int iy = y + dy - 1;
#pragma unroll
    for (int dx = 0; dx < 3; ++dx) {
      int ix = xx + dx - 1;
      if (iy >= 0 && iy < 28 && ix >= 0 && ix < 28)
        a = fmaf(w1[c * 9 + dy * 3 + dx], x[b * 784 + iy * 28 + ix], a);
    }
  }
  float inv  = g1[c] / sqrtf(v1[c] + 1e-5f);
  float bias = __fsub_rn(b1[c], __fmul_rn(m1[c], inv));
  h1[i] = __fadd_rn(__fmul_rn(a, inv), bias);
}

// ---------------- LIF1 + maxpool -> p1 (u8, channels-last halo [pix][ci]) ----------------
__global__ __launch_bounds__(256) void k_lif1pool(const float* __restrict__ h1,
                                                  unsigned char* __restrict__ p1) {
  int t = blockIdx.x * 256 + threadIdx.x;      // < 262144
  int ci = t & 63, xx = (t >> 6) & 15, y = (t >> 10) & 15, b = t >> 14;
  int pix = y * 16 + xx;
  size_t outbase = (size_t)b * 16384 + pix * 64 + ci;
  const size_t tstride = (size_t)16 * 16384;
  if (y == 0 || y == 15 || xx == 0 || xx == 15) {
    for (int tt = 0; tt < T_STEPS; ++tt) p1[outbase + (size_t)tt * tstride] = 0;
    return;
  }
  int py = y - 1, px = xx - 1;
  const float* hp = h1 + ((size_t)(b * 64 + ci) * 28 + 2 * py) * 28 + 2 * px;
  float h00 = hp[0], h01 = hp[1], h10 = hp[28], h11 = hp[29];
  float v00 = 0.f, v01 = 0.f, v10 = 0.f, v11 = 0.f;
  for (int tt = 0; tt < T_STEPS; ++tt) {
    int s = 0;
    s |= lif_step_i(v00, h00);
    s |= lif_step_i(v01, h01);
    s |= lif_step_i(v10, h10);
    s |= lif_step_i(v11, h11);
    p1[outbase + (size_t)tt * tstride] = (unsigned char)s;
  }
}

// ---------------- conv2 + BN2 via MFMA, kb-outer / oy-inner (weights in regs) ----------------
// block = 1 image, 4 waves. wave: cohalf = w&1, oy rows (w>>1)*7..+7.
// Per kb (18): load 4 weight frags ONCE, then 7x { 1 ds_read_b128 B-frag, 4 MFMA }.
// Weight traffic per block: 288 KB (was 2 MB) -> stays L2-hot.
__global__ __launch_bounds__(256, 2) void k_conv2(const unsigned char* __restrict__ p1,
                                                  const f16* __restrict__ whi, const f16* __restrict__ wlo,
                                                  const float* __restrict__ g2, const float* __restrict__ b2,
                                                  const float* __restrict__ m2, const float* __restrict__ v2,
                                                  float* __restrict__ h2) {
  __shared__ unsigned char smem[33024];        // 258 rows * 128B, XOR-swizzled
  const int tid = threadIdx.x;
  const int tb = blockIdx.x;
  const unsigned char* img = p1 + (size_t)tb * 16384;
#pragma unroll
  for (int it = 0; it < 4; ++it) {
    int s = it * 256 + tid;
    uint4 d = *(const uint4*)(img + (size_t)s * 16);
    int pix = s >> 2, c4 = s & 3;
    uint dw[4] = {d.x, d.y, d.z, d.w};
    f16x8 va, vb;
#pragma unroll
    for (int e = 0; e < 8; ++e) {
      va[e] = (f16)(float)((dw[e >> 2] >> ((e & 3) * 8)) & 255u);
      vb[e] = (f16)(float)((dw[2 + (e >> 2)] >> ((e & 3) * 8)) & 255u);
    }
    int rowbase = pix * 128;
    int sw = (pix & 7) << 4;
    *(f16x8*)(smem + rowbase + ((c4 * 32) ^ sw)) = va;
    *(f16x8*)(smem + rowbase + ((c4 * 32 + 16) ^ sw)) = vb;
  }
  if (tid < 16) *(uint4*)(smem + 32768 + tid * 16) = make_uint4(0u, 0u, 0u, 0u);
  __syncthreads();

  const int lane = tid & 63;
  const int wave = tid >> 6;
  const int ox = lane & 15;
  const int g = lane >> 4;
  const int cohalf = wave & 1;
  const int pb0 = (wave >> 1) * 7;

  f32x4 aH0[7], aL0[7], aH1[7], aL1[7];
#pragma unroll
  for (int q = 0; q < 7; ++q) {
    aH0[q] = (f32x4){0.f, 0.f, 0.f, 0.f};
    aL0[q] = (f32x4){0.f, 0.f, 0.f, 0.f};
    aH1[q] = (f32x4){0.f, 0.f, 0.f, 0.f};
    aL1[q] = (f32x4){0.f, 0.f, 0.f, 0.f};
  }

#pragma unroll 2
  for (int kb = 0; kb < 18; ++kb) {
    const int tap = kb >> 1;
    const int dy = tap / 3, dx = tap - 3 * dy;
    const int cilo2 = (kb & 1) * 64;
    size_t abase = ((size_t)(kb * 4 + cohalf * 2) * 64 + lane) * 8;
    f16x8 ah0 = *(const f16x8*)(whi + abase);
    f16x8 al0 = *(const f16x8*)(wlo + abase);
    f16x8 ah1 = *(const f16x8*)(whi + abase + 512);
    f16x8 al1 = *(const f16x8*)(wlo + abase + 512);
#pragma unroll
    for (int q = 0; q < 7; ++q) {
      int pix = (pb0 + q + dy) * 16 + ox + dx;
      int boff = pix * 128 + ((cilo2 + g * 16) ^ ((pix & 7) << 4));
      f16x8 bf = *(const f16x8*)(smem + boff);
      aH0[q] = __builtin_amdgcn_mfma_f32_16x16x32_f16(ah0, bf, aH0[q], 0, 0, 0);
      aL0[q] = __builtin_amdgcn_mfma_f32_16x16x32_f16(al0, bf, aL0[q], 0, 0, 0);
      aH1[q] = __builtin_amdgcn_mfma_f32_16x16x32_f16(ah1, bf, aH1[q], 0, 0, 0);
      aL1[q] = __builtin_amdgcn_mfma_f32_16x16x32_f16(al1, bf, aL1[q], 0, 0, 0);
    }
  }

  float binv[2][4], bofs[2][4];
#pragma unroll
  for (int cb = 0; cb < 2; ++cb)
#pragma unroll
    for (int r = 0; r < 4; ++r) {
      int co = (cohalf * 2 + cb) * 16 + g * 4 + r;
      float iv = g2[co] / sqrtf(v2[co] + 1e-5f);
      binv[cb][r] = iv;
      bofs[cb][r] = __fsub_rn(b2[co], __fmul_rn(m2[co], iv));
    }

  if (ox < 14) {
#pragma unroll
    for (int q = 0; q < 7; ++q) {
      int oy = pb0 + q;
#pragma unroll
      for (int r = 0; r < 4; ++r) {
        int co0 = cohalf * 32 + g * 4 + r;
        float s0 = __fadd_rn(aH0[q][r], __fmul_rn(aL0[q][r], 1.0f / 4096.0f));
        h2[((size_t)tb * 64 + co0) * 196 + oy * 14 + ox] =
            __fadd_rn(__fmul_rn(s0, binv[0][r]), bofs[0][r]);
        int co1 = co0 + 16;
        float s1 = __fadd_rn(aH1[q][r], __fmul_rn(aL1[q][r], 1.0f / 4096.0f));
        h2[((size_t)tb * 64 + co1) * 196 + oy * 14 + ox] =
            __fadd_rn(__fmul_rn(s1, binv[1][r]), bofs[1][r]);
      }
    }
  }
}

// ---------------- LIF2 + maxpool -> p2 (u8) ----------------
__global__ __launch_bounds__(256) void k_lif2pool(const float* __restrict__ h2,
                                                  unsigned char* __restrict__ p2) {
  int t = blockIdx.x * 256 + threadIdx.x;      // < 50176
  int px = t % 7;
  int r1 = t / 7;
  int py = r1 % 7;
  int r2 = r1 / 7;
  int c = r2 & 63, b = r2 >> 6;
  const float* base = h2 + ((size_t)b * 64 + c) * 196 + (2 * py) * 14 + 2 * px;
  const size_t tstride = (size_t)16 * 64 * 196;
  unsigned char* op = p2 + (size_t)b * 3136 + c * 49 + py * 7 + px;
  const size_t otstride = (size_t)16 * 3136;
  float v00 = 0.f, v01 = 0.f, v10 = 0.f, v11 = 0.f;
#pragma unroll 4
  for (int tt = 0; tt < T_STEPS; ++tt) {
    const float* hp = base + (size_t)tt * tstride;
    float2 r0 = *(const float2*)(hp);
    float2 r1v = *(const float2*)(hp + 14);
    int s = 0;
    s |= lif_step_i(v00, r0.x);
    s |= lif_step_i(v01, r0.y);
    s |= lif_step_i(v10, r1v.x);
    s |= lif_step_i(v11, r1v.y);
    op[(size_t)tt * otstride] = (unsigned char)s;
  }
}

// ---------------- FC1 (split-K=2, deterministic atomic) ----------------
__global__ __launch_bounds__(256) void k_fc1(const unsigned char* __restrict__ p2,
                                             const float* __restrict__ wfc1,
                                             float* __restrict__ h3) {
  __shared__ float As[32][128];
  __shared__ float Bs[32][128];
  const int t = threadIdx.x;
  const int r = t & 127, half = t >> 7;
  const int tb0 = blockIdx.x * 128;
  const int o0  = blockIdx.y * 128;
  const int k0  = blockIdx.z * 1568;
  const int ig = t >> 4, jg = t & 15;
  float acc[8][8];
#pragma unroll
  for (int a = 0; a < 8; ++a)
#pragma unroll
    for (int bb = 0; bb < 8; ++bb) acc[a][bb] = 0.f;

  for (int ch = 0; ch < 49; ++ch) {
    int kb = k0 + ch * 32;
    __syncthreads();
    {
      int tb = tb0 + r;
      uint4 bytes = make_uint4(0u, 0u, 0u, 0u);
      if (tb < 1600) bytes = *(const uint4*)(p2 + (size_t)tb * 3136 + kb + half * 16);
      uint w4[4] = {bytes.x, bytes.y, bytes.z, bytes.w};
#pragma unroll
      for (int j = 0; j < 16; ++j)
        As[half * 16 + j][r] = (float)((w4[j >> 2] >> ((j & 3) * 8)) & 255u);
    }
    {
      const float* wrow = wfc1 + (size_t)(o0 + r) * 3136 + kb + half * 16;
#pragma unroll
      for (int j = 0; j < 4; ++j) {
        float4 d = *(const float4*)(wrow + j * 4);
        int kk = half * 16 + j * 4;
        Bs[kk + 0][r] = d.x; Bs[kk + 1][r] = d.y; Bs[kk + 2][r] = d.z; Bs[kk + 3][r] = d.w;
      }
    }
    __syncthreads();
#pragma unroll 8
    for (int kk = 0; kk < 32; ++kk) {
      float4 a0 = *(const float4*)&As[kk][ig * 8];
      float4 a1 = *(const float4*)&As[kk][ig * 8 + 4];
      float4 b0 = *(const float4*)&Bs[kk][jg * 8];
      float4 b1 = *(const float4*)&Bs[kk][jg * 8 + 4];
      float av[8] = {a0.x, a0.y, a0.z, a0.w, a1.x, a1.y, a1.z, a1.w};
      float bv[8] = {b0.x, b0.y, b0.z, b0.w, b1.x, b1.y, b1.z, b1.w};
#pragma unroll
      for (int a = 0; a < 8; ++a)
#pragma unroll
        for (int bb = 0; bb < 8; ++bb)
          acc[a][bb] = fmaf(av[a], bv[bb], acc[a][bb]);
    }
  }
#pragma unroll
  for (int a = 0; a < 8; ++a) {
    int tb = tb0 + ig * 8 + a;
    if (tb < 1600) {
#pragma unroll
      for (int bb = 0; bb < 8; ++bb)
        atomicAdd(&h3[(size_t)tb * 1024 + o0 + jg * 8 + bb], acc[a][bb]);
    }
  }
}

// ---------------- LIF3 -> s3 (u8) ----------------
__global__ __launch_bounds__(256) void k_lif3(const float* __restrict__ h3,
                                              unsigned char* __restrict__ s3) {
  int t = blockIdx.x * 256 + threadIdx.x;      // < 16384
  int o = t & 1023, b = t >> 10;
  size_t base = (size_t)b * 1024 + o;
  float v = 0.f;
#pragma unroll 5
  for (int tt = 0; tt < T_STEPS; ++tt) {
    float xv = h3[base + (size_t)tt * 16384];
    s3[base + (size_t)tt * 16384] = (unsigned char)lif_step_i(v, xv);
  }
}

// ---------------- FC2 ----------------
__global__ __launch_bounds__(64) void k_fc2(const unsigned char* __restrict__ s3,
                                            const float* __restrict__ wfc2,
                                            float* __restrict__ h4) {
  int tb = blockIdx.x;                          // < 1600
  int l = threadIdx.x;
  const unsigned char* srow = s3 + (size_t)tb * 1024;
  float p[10];
#pragma unroll
  for (int o = 0; o < 10; ++o) p[o] = 0.f;
  for (int j = 0; j < 16; ++j) {
    int k = l + j * 64;
    float s = (float)srow[k];
#pragma unroll
    for (int o = 0; o < 10; ++o)
      p[o] = fmaf(s, wfc2[o * 1024 + k], p[o]);
  }
#pragma unroll
  for (int o = 0; o < 10; ++o) {
    float v = p[o];
    for (int off = 32; off > 0; off >>= 1) v += __shfl_down(v, off, 64);
    if (l == 0) h4[(size_t)tb * 10 + o] = v;
  }
}

// ---------------- LIF4 + mean ----------------
__global__ __launch_bounds__(256) void k_lif4mean(const float* __restrict__ h4,
                                                  float* __restrict__ out) {
  int t = threadIdx.x;
  if (t >= 160) return;
  int o = t % 10, b = t / 10;
  float v = 0.f;
  int cnt = 0;
#pragma unroll 10
  for (int tt = 0; tt < T_STEPS; ++tt) {
    float xv = h4[(size_t)tt * 160 + b * 10 + o];
    cnt += lif_step_i(v, xv);
  }
  out[b * 10 + o] = (float)cnt / 100.0f;
}

extern "C" void kernel_launch(void* const* d_in, const int* in_sizes, int n_in,
                              void* d_out, int out_size, void* d_ws, size_t ws_size,
                              hipStream_t stream) {
  const float* x    = (const float*)d_in[0];
  const float* W1   = (const float*)d_in[1];
  const float* g1   = (const float*)d_in[2];
  const float* b1   = (const float*)d_in[3];
  const float* m1   = (const float*)d_in[4];
  const float* v1   = (const float*)d_in[5];
  const float* W2   = (const float*)d_in[6];
  const float* g2   = (const float*)d_in[7];
  const float* b2   = (const float*)d_in[8];
  const float* m2   = (const float*)d_in[9];
  const float* v2   = (const float*)d_in[10];
  const float* Wfc1 = (const float*)d_in[11];
  const float* Wfc2 = (const float*)d_in[12];
  float* out = (float*)d_out;
  char* ws = (char*)d_ws;

  float*         h1  = (float*)(ws + OFF_H1);
  f16*           whi = (f16*)(ws + OFF_WHI);
  f16*           wlo = (f16*)(ws + OFF_WLO);
  unsigned char* p1  = (unsigned char*)(ws + OFF_P1);
  float*         h2  = (float*)(ws + OFF_H2);
  unsigned char* p2  = (unsigned char*)(ws + OFF_P2);
  float*         h3  = (float*)(ws + OFF_H3);
  unsigned char* s3  = (unsigned char*)(ws + OFF_S3);
  float*         h4  = (float*)(ws + OFF_H4);

  k_conv1<<<3136, 256, 0, stream>>>(x, W1, g1, b1, m1, v1, h1);
  k_lif1pool<<<1024, 256, 0, stream>>>(h1, p1);
  k_prep_w2<<<144, 256, 0, stream>>>(W2, whi, wlo);   // overlays dead h1
  k_conv2<<<1600, 256, 0, stream>>>(p1, whi, wlo, g2, b2, m2, v2, h2);
  k_lif2pool<<<196, 256, 0, stream>>>(h2, p2);
  k_zero_h3<<<1600, 256, 0, stream>>>((float4*)h3);   // overlays dead h2
  dim3 gfc1(13, 8, 2);
  k_fc1<<<gfc1, 256, 0, stream>>>(p2, Wfc1, h3);
  k_lif3<<<64, 256, 0, stream>>>(h3, s3);
  k_fc2<<<1600, 64, 0, stream>>>(s3, Wfc2, h4);
  k_lif4mean<<<1, 256, 0, stream>>>(h4, out);
}

// Round 5
// 278.638 us; speedup vs baseline: 4.2997x; 1.8770x over previous
//
#include <hip/hip_runtime.h>
#include <hip/hip_bf16.h>

typedef unsigned int uint;
typedef _Float16 f16;
typedef _Float16 f16x8 __attribute__((ext_vector_type(8)));
typedef float f32x4 __attribute__((ext_vector_type(4)));

#define T_STEPS 100

// ---------------- ws layout (bytes), with overlays ----------------
#define OFF_H1    (size_t)0
#define OFF_WHI   (size_t)0            // conv2 packs overlay dead h1
#define OFF_WLO   (size_t)73728
#define OFF_P1    (size_t)3211264
#define OFF_H2    (size_t)29425664     // dead after lif2pool; overlays below
#define OFF_H3    (size_t)29425664     //   6,553,600
#define OFF_S3    (size_t)35979264     //   1,638,400
#define OFF_H4    (size_t)37617664     //     64,000
#define OFF_WF1L  (size_t)37681664     //   6,422,528 (fc1 lo pack, after lif2pool)
#define OFF_P2    (size_t)109707264    //   5,017,600
#define OFF_WF1H  (size_t)114724864    //   6,422,528 (tail; ends 121,147,392 < proven 123MB)

__device__ __forceinline__ int lif_step_i(float& v, float x) {
  v = __fadd_rn(v, __fmul_rn(__fsub_rn(x, v), 0.5f));
  if (v >= 1.0f) { v = 0.0f; return 1; }
  return 0;
}

// ---------------- conv2 weight prep: fragment-major fp16 hi/lo split ----------------
__global__ __launch_bounds__(256) void k_prep_w2(const float* __restrict__ w2,
                                                 f16* __restrict__ whi, f16* __restrict__ wlo) {
  int i = blockIdx.x * 256 + threadIdx.x;       // < 36864
  int j = i & 7, l = (i >> 3) & 63, cb = (i >> 9) & 3, kb = i >> 11;
  int k = kb * 32 + (l >> 4) * 8 + j;
  int co = cb * 16 + (l & 15);
  int ci = k & 63, tap = k >> 6;
  int dy = tap / 3, dx = tap - 3 * dy;
  float w = w2[((co * 64 + ci) * 3 + dy) * 3 + dx];
  float hif = (fabsf(w) < 6.104e-5f) ? 0.0f : (float)(f16)w;
  whi[i] = (f16)hif;
  wlo[i] = (f16)((w - hif) * 4096.0f);
}

// ---------------- fc1 weight prep: fragment-major fp16 hi/lo split ----------------
// packed i = ((kbG*64 + oblk)*64 + lane)*8 + j ; o = oblk*16+(lane&15), k = kbG*32+(lane>>4)*8+j
__global__ __launch_bounds__(256) void k_prep_wfc1(const float* __restrict__ wfc1,
                                                   f16* __restrict__ whi, f16* __restrict__ wlo) {
  int i = blockIdx.x * 256 + threadIdx.x;       // < 3,211,264
  int j = i & 7, lane = (i >> 3) & 63;
  int rest = i >> 9;
  int oblk = rest & 63, kbG = rest >> 6;        // kbG < 98
  int o = oblk * 16 + (lane & 15);
  int k = kbG * 32 + (lane >> 4) * 8 + j;
  float w = wfc1[(size_t)o * 3136 + k];
  float hif = (fabsf(w) < 6.104e-5f) ? 0.0f : (float)(f16)w;
  whi[i] = (f16)hif;
  wlo[i] = (f16)((w - hif) * 4096.0f);
}

__global__ __launch_bounds__(256) void k_zero_h3(float4* __restrict__ p) {
  p[blockIdx.x * 256 + threadIdx.x] = make_float4(0.f, 0.f, 0.f, 0.f);
}

// ---------------- conv1 + BN1 ----------------
__global__ __launch_bounds__(256) void k_conv1(const float* __restrict__ x, const float* __restrict__ w1,
                                               const float* __restrict__ g1, const float* __restrict__ b1,
                                               const float* __restrict__ m1, const float* __restrict__ v1,
                                               float* __restrict__ h1) {
  int i = blockIdx.x * 256 + threadIdx.x;      // < 802816
  int pos = i % 784;
  int bc  = i / 784;
  int c = bc & 63, b = bc >> 6;
  int y = pos / 28, xx = pos % 28;
  float a = 0.f;
#pragma unroll
  for (int dy = 0; dy < 3; ++dy) {
    int iy = y + dy - 1;
#pragma unroll
    for (int dx = 0; dx < 3; ++dx) {
      int ix = xx + dx - 1;
      if (iy >= 0 && iy < 28 && ix >= 0 && ix < 28)
        a = fmaf(w1[c * 9 + dy * 3 + dx], x[b * 784 + iy * 28 + ix], a);
    }
  }
  float inv  = g1[c] / sqrtf(v1[c] + 1e-5f);
  float bias = __fsub_rn(b1[c], __fmul_rn(m1[c], inv));
  h1[i] = __fadd_rn(__fmul_rn(a, inv), bias);
}

// ---------------- LIF1 + maxpool -> p1 (u8, channels-last halo [pix][ci]) ----------------
__global__ __launch_bounds__(256) void k_lif1pool(const float* __restrict__ h1,
                                                  unsigned char* __restrict__ p1) {
  int t = blockIdx.x * 256 + threadIdx.x;      // < 262144
  int ci = t & 63, xx = (t >> 6) & 15, y = (t >> 10) & 15, b = t >> 14;
  int pix = y * 16 + xx;
  size_t outbase = (size_t)b * 16384 + pix * 64 + ci;
  const size_t tstride = (size_t)16 * 16384;
  if (y == 0 || y == 15 || xx == 0 || xx == 15) {
    for (int tt = 0; tt < T_STEPS; ++tt) p1[outbase + (size_t)tt * tstride] = 0;
    return;
  }
  int py = y - 1, px = xx - 1;
  const float* hp = h1 + ((size_t)(b * 64 + ci) * 28 + 2 * py) * 28 + 2 * px;
  float h00 = hp[0], h01 = hp[1], h10 = hp[28], h11 = hp[29];
  float v00 = 0.f, v01 = 0.f, v10 = 0.f, v11 = 0.f;
  for (int tt = 0; tt < T_STEPS; ++tt) {
    int s = 0;
    s |= lif_step_i(v00, h00);
    s |= lif_step_i(v01, h01);
    s |= lif_step_i(v10, h10);
    s |= lif_step_i(v11, h11);
    p1[outbase + (size_t)tt * tstride] = (unsigned char)s;
  }
}

// ---------------- conv2 + BN2 via MFMA, kb-outer / oy-inner (weights in regs) ----------------
__global__ __launch_bounds__(256, 2) void k_conv2(const unsigned char* __restrict__ p1,
                                                  const f16* __restrict__ whi, const f16* __restrict__ wlo,
                                                  const float* __restrict__ g2, const float* __restrict__ b2,
                                                  const float* __restrict__ m2, const float* __restrict__ v2,
                                                  float* __restrict__ h2) {
  __shared__ unsigned char smem[33024];        // 258 rows * 128B, XOR-swizzled
  const int tid = threadIdx.x;
  const int tb = blockIdx.x;
  const unsigned char* img = p1 + (size_t)tb * 16384;
#pragma unroll
  for (int it = 0; it < 4; ++it) {
    int s = it * 256 + tid;
    uint4 d = *(const uint4*)(img + (size_t)s * 16);
    int pix = s >> 2, c4 = s & 3;
    uint dw[4] = {d.x, d.y, d.z, d.w};
    f16x8 va, vb;
#pragma unroll
    for (int e = 0; e < 8; ++e) {
      va[e] = (f16)(float)((dw[e >> 2] >> ((e & 3) * 8)) & 255u);
      vb[e] = (f16)(float)((dw[2 + (e >> 2)] >> ((e & 3) * 8)) & 255u);
    }
    int rowbase = pix * 128;
    int sw = (pix & 7) << 4;
    *(f16x8*)(smem + rowbase + ((c4 * 32) ^ sw)) = va;
    *(f16x8*)(smem + rowbase + ((c4 * 32 + 16) ^ sw)) = vb;
  }
  if (tid < 16) *(uint4*)(smem + 32768 + tid * 16) = make_uint4(0u, 0u, 0u, 0u);
  __syncthreads();

  const int lane = tid & 63;
  const int wave = tid >> 6;
  const int ox = lane & 15;
  const int g = lane >> 4;
  const int cohalf = wave & 1;
  const int pb0 = (wave >> 1) * 7;

  f32x4 aH0[7], aL0[7], aH1[7], aL1[7];
#pragma unroll
  for (int q = 0; q < 7; ++q) {
    aH0[q] = (f32x4){0.f, 0.f, 0.f, 0.f};
    aL0[q] = (f32x4){0.f, 0.f, 0.f, 0.f};
    aH1[q] = (f32x4){0.f, 0.f, 0.f, 0.f};
    aL1[q] = (f32x4){0.f, 0.f, 0.f, 0.f};
  }

#pragma unroll 2
  for (int kb = 0; kb < 18; ++kb) {
    const int tap = kb >> 1;
    const int dy = tap / 3, dx = tap - 3 * dy;
    const int cilo2 = (kb & 1) * 64;
    size_t abase = ((size_t)(kb * 4 + cohalf * 2) * 64 + lane) * 8;
    f16x8 ah0 = *(const f16x8*)(whi + abase);
    f16x8 al0 = *(const f16x8*)(wlo + abase);
    f16x8 ah1 = *(const f16x8*)(whi + abase + 512);
    f16x8 al1 = *(const f16x8*)(wlo + abase + 512);
#pragma unroll
    for (int q = 0; q < 7; ++q) {
      int pix = (pb0 + q + dy) * 16 + ox + dx;
      int boff = pix * 128 + ((cilo2 + g * 16) ^ ((pix & 7) << 4));
      f16x8 bf = *(const f16x8*)(smem + boff);
      aH0[q] = __builtin_amdgcn_mfma_f32_16x16x32_f16(ah0, bf, aH0[q], 0, 0, 0);
      aL0[q] = __builtin_amdgcn_mfma_f32_16x16x32_f16(al0, bf, aL0[q], 0, 0, 0);
      aH1[q] = __builtin_amdgcn_mfma_f32_16x16x32_f16(ah1, bf, aH1[q], 0, 0, 0);
      aL1[q] = __builtin_amdgcn_mfma_f32_16x16x32_f16(al1, bf, aL1[q], 0, 0, 0);
    }
  }

  float binv[2][4], bofs[2][4];
#pragma unroll
  for (int cb = 0; cb < 2; ++cb)
#pragma unroll
    for (int r = 0; r < 4; ++r) {
      int co = (cohalf * 2 + cb) * 16 + g * 4 + r;
      float iv = g2[co] / sqrtf(v2[co] + 1e-5f);
      binv[cb][r] = iv;
      bofs[cb][r] = __fsub_rn(b2[co], __fmul_rn(m2[co], iv));
    }

  if (ox < 14) {
#pragma unroll
    for (int q = 0; q < 7; ++q) {
      int oy = pb0 + q;
#pragma unroll
      for (int r = 0; r < 4; ++r) {
        int co0 = cohalf * 32 + g * 4 + r;
        float s0 = __fadd_rn(aH0[q][r], __fmul_rn(aL0[q][r], 1.0f / 4096.0f));
        h2[((size_t)tb * 64 + co0) * 196 + oy * 14 + ox] =
            __fadd_rn(__fmul_rn(s0, binv[0][r]), bofs[0][r]);
        int co1 = co0 + 16;
        float s1 = __fadd_rn(aH1[q][r], __fmul_rn(aL1[q][r], 1.0f / 4096.0f));
        h2[((size_t)tb * 64 + co1) * 196 + oy * 14 + ox] =
            __fadd_rn(__fmul_rn(s1, binv[1][r]), bofs[1][r]);
      }
    }
  }
}

// ---------------- LIF2 + maxpool -> p2 (u8) ----------------
__global__ __launch_bounds__(256) void k_lif2pool(const float* __restrict__ h2,
                                                  unsigned char* __restrict__ p2) {
  int t = blockIdx.x * 256 + threadIdx.x;      // < 50176
  int px = t % 7;
  int r1 = t / 7;
  int py = r1 % 7;
  int r2 = r1 / 7;
  int c = r2 & 63, b = r2 >> 6;
  const float* base = h2 + ((size_t)b * 64 + c) * 196 + (2 * py) * 14 + 2 * px;
  const size_t tstride = (size_t)16 * 64 * 196;
  unsigned char* op = p2 + (size_t)b * 3136 + c * 49 + py * 7 + px;
  const size_t otstride = (size_t)16 * 3136;
  float v00 = 0.f, v01 = 0.f, v10 = 0.f, v11 = 0.f;
#pragma unroll 4
  for (int tt = 0; tt < T_STEPS; ++tt) {
    const float* hp = base + (size_t)tt * tstride;
    float2 r0 = *(const float2*)(hp);
    float2 r1v = *(const float2*)(hp + 14);
    int s = 0;
    s |= lif_step_i(v00, r0.x);
    s |= lif_step_i(v01, r0.y);
    s |= lif_step_i(v10, r1v.x);
    s |= lif_step_i(v11, r1v.y);
    op[(size_t)tt * otstride] = (unsigned char)s;
  }
}

// ---------------- FC1 via MFMA (fp16 hi/lo), split-K=2, deterministic 2-atomic ----------------
// grid (13, 16, 2): 128 tb x 64 o tiles. 4 waves: wave = o-16-block. LDS B dbuf [2][128][80B].
__global__ __launch_bounds__(256, 2) void k_fc1(const unsigned char* __restrict__ p2,
                                                const f16* __restrict__ whi, const f16* __restrict__ wlo,
                                                float* __restrict__ h3) {
  __shared__ unsigned char bsm[2][128 * 80];   // f16 [tb][40], row 80B (5x16B -> low conflict)
  const int tid = threadIdx.x;
  const int lane = tid & 63;
  const int wave = tid >> 6;
  const int tb0 = blockIdx.x * 128;
  const int oblk = blockIdx.y * 4 + wave;      // o-16-block, < 64
  const int z = blockIdx.z;                    // K half
  const int tbl = tid >> 1, kslot = tid & 1;   // staging role
  const int stb = tb0 + tbl;
  const unsigned char* sp = p2 + (size_t)stb * 3136 + z * 1568 + kslot * 16;
  const bool sok = (stb < 1600);

  f32x4 accH[8], accL[8];
#pragma unroll
  for (int n = 0; n < 8; ++n) {
    accH[n] = (f32x4){0.f, 0.f, 0.f, 0.f};
    accL[n] = (f32x4){0.f, 0.f, 0.f, 0.f};
  }

  // A fragment pointers (packed fragment-major)
  const int kbG0 = z * 49;
  size_t afrag = ((size_t)(kbG0 * 64 + oblk) * 64 + lane) * 8;
  const size_t astep = (size_t)64 * 64 * 8;    // per kbG
  f16x8 ahC = *(const f16x8*)(whi + afrag);
  f16x8 alC = *(const f16x8*)(wlo + afrag);

  for (int kb = 0; kb < 49; ++kb) {
    // stage B for this kb
    uint4 d = make_uint4(0u, 0u, 0u, 0u);
    if (sok) d = *(const uint4*)(sp + kb * 32);
    // prefetch next A frags
    f16x8 ahN, alN;
    if (kb < 48) {
      ahN = *(const f16x8*)(whi + afrag + (kb + 1) * astep);
      alN = *(const f16x8*)(wlo + afrag + (kb + 1) * astep);
    }
    uint dw[4] = {d.x, d.y, d.z, d.w};
    f16x8 va, vb;
#pragma unroll
    for (int e = 0; e < 8; ++e) {
      va[e] = (f16)(float)((dw[e >> 2] >> ((e & 3) * 8)) & 255u);
      vb[e] = (f16)(float)((dw[2 + (e >> 2)] >> ((e & 3) * 8)) & 255u);
    }
    unsigned char* row = &bsm[kb & 1][tbl * 80];
    *(f16x8*)(row + kslot * 32) = va;
    *(f16x8*)(row + kslot * 32 + 16) = vb;
    __syncthreads();
    const unsigned char* buf = &bsm[kb & 1][0];
#pragma unroll
    for (int n = 0; n < 8; ++n) {
      f16x8 bf = *(const f16x8*)(buf + (n * 16 + (lane & 15)) * 80 + (lane >> 4) * 16);
      accH[n] = __builtin_amdgcn_mfma_f32_16x16x32_f16(ahC, bf, accH[n], 0, 0, 0);
      accL[n] = __builtin_amdgcn_mfma_f32_16x16x32_f16(alC, bf, accL[n], 0, 0, 0);
    }
    ahC = ahN; alC = alN;
  }

  const int o = blockIdx.y * 64 + wave * 16 + (lane >> 4) * 4;  // + r
#pragma unroll
  for (int n = 0; n < 8; ++n) {
    int tb = tb0 + n * 16 + (lane & 15);
    if (tb < 1600) {
      float* hp = h3 + (size_t)tb * 1024 + o;
#pragma unroll
      for (int r = 0; r < 4; ++r) {
        float s = __fadd_rn(accH[n][r], __fmul_rn(accL[n][r], 1.0f / 4096.0f));
        atomicAdd(hp + r, s);
      }
    }
  }
}

// ---------------- LIF3 -> s3 (u8) ----------------
__global__ __launch_bounds__(256) void k_lif3(const float* __restrict__ h3,
                                              unsigned char* __restrict__ s3) {
  int t = blockIdx.x * 256 + threadIdx.x;      // < 16384
  int o = t & 1023, b = t >> 10;
  size_t base = (size_t)b * 1024 + o;
  float v = 0.f;
#pragma unroll 5
  for (int tt = 0; tt < T_STEPS; ++tt) {
    float xv = h3[base + (size_t)tt * 16384];
    s3[base + (size_t)tt * 16384] = (unsigned char)lif_step_i(v, xv);
  }
}

// ---------------- FC2 ----------------
__global__ __launch_bounds__(64) void k_fc2(const unsigned char* __restrict__ s3,
                                            const float* __restrict__ wfc2,
                                            float* __restrict__ h4) {
  int tb = blockIdx.x;                          // < 1600
  int l = threadIdx.x;
  const unsigned char* srow = s3 + (size_t)tb * 1024;
  float p[10];
#pragma unroll
  for (int o = 0; o < 10; ++o) p[o] = 0.f;
  for (int j = 0; j < 16; ++j) {
    int k = l + j * 64;
    float s = (float)srow[k];
#pragma unroll
    for (int o = 0; o < 10; ++o)
      p[o] = fmaf(s, wfc2[o * 1024 + k], p[o]);
  }
#pragma unroll
  for (int o = 0; o < 10; ++o) {
    float v = p[o];
    for (int off = 32; off > 0; off >>= 1) v += __shfl_down(v, off, 64);
    if (l == 0) h4[(size_t)tb * 10 + o] = v;
  }
}

// ---------------- LIF4 + mean ----------------
__global__ __launch_bounds__(256) void k_lif4mean(const float* __restrict__ h4,
                                                  float* __restrict__ out) {
  int t = threadIdx.x;
  if (t >= 160) return;
  int o = t % 10, b = t / 10;
  float v = 0.f;
  int cnt = 0;
#pragma unroll 10
  for (int tt = 0; tt < T_STEPS; ++tt) {
    float xv = h4[(size_t)tt * 160 + b * 10 + o];
    cnt += lif_step_i(v, xv);
  }
  out[b * 10 + o] = (float)cnt / 100.0f;
}

extern "C" void kernel_launch(void* const* d_in, const int* in_sizes, int n_in,
                              void* d_out, int out_size, void* d_ws, size_t ws_size,
                              hipStream_t stream) {
  const float* x    = (const float*)d_in[0];
  const float* W1   = (const float*)d_in[1];
  const float* g1   = (const float*)d_in[2];
  const float* b1   = (const float*)d_in[3];
  const float* m1   = (const float*)d_in[4];
  const float* v1   = (const float*)d_in[5];
  const float* W2   = (const float*)d_in[6];
  const float* g2   = (const float*)d_in[7];
  const float* b2   = (const float*)d_in[8];
  const float* m2   = (const float*)d_in[9];
  const float* v2   = (const float*)d_in[10];
  const float* Wfc1 = (const float*)d_in[11];
  const float* Wfc2 = (const float*)d_in[12];
  float* out = (float*)d_out;
  char* ws = (char*)d_ws;

  float*         h1   = (float*)(ws + OFF_H1);
  f16*           whi  = (f16*)(ws + OFF_WHI);
  f16*           wlo  = (f16*)(ws + OFF_WLO);
  unsigned char* p1   = (unsigned char*)(ws + OFF_P1);
  float*         h2   = (float*)(ws + OFF_H2);
  unsigned char* p2   = (unsigned char*)(ws + OFF_P2);
  float*         h3   = (float*)(ws + OFF_H3);
  unsigned char* s3   = (unsigned char*)(ws + OFF_S3);
  float*         h4   = (float*)(ws + OFF_H4);
  f16*           wf1h = (f16*)(ws + OFF_WF1H);
  f16*           wf1l = (f16*)(ws + OFF_WF1L);

  k_conv1<<<3136, 256, 0, stream>>>(x, W1, g1, b1, m1, v1, h1);
  k_lif1pool<<<1024, 256, 0, stream>>>(h1, p1);
  k_prep_w2<<<144, 256, 0, stream>>>(W2, whi, wlo);        // overlays dead h1
  k_conv2<<<1600, 256, 0, stream>>>(p1, whi, wlo, g2, b2, m2, v2, h2);
  k_lif2pool<<<196, 256, 0, stream>>>(h2, p2);
  k_prep_wfc1<<<12544, 256, 0, stream>>>(Wfc1, wf1h, wf1l); // overlays dead h2 + tail
  k_zero_h3<<<1600, 256, 0, stream>>>((float4*)h3);
  dim3 gfc1(13, 16, 2);
  k_fc1<<<gfc1, 256, 0, stream>>>(p2, wf1h, wf1l, h3);
  k_lif3<<<64, 256, 0, stream>>>(h3, s3);
  k_fc2<<<1600, 64, 0, stream>>>(s3, Wfc2, h4);
  k_lif4mean<<<1, 256, 0, stream>>>(h4, out);
}